// Round 13
// baseline (364.102 us; speedup 1.0000x reference)
//
#include <hip/hip_runtime.h>
#include <hip/hip_cooperative_groups.h>

namespace cg = cooperative_groups;

#define ALG_DIM 248
#define ROWS 32                    // rows per tile in the main phase
#define KSPLIT 4
#define KPB 62                     // k-slots per tile (248/4)
#define PMAX 1024                  // safety clamp for padded bucket length
#define CB 32                      // prep chunk blocks
#define PLSTRIDE_B 3984            // plane stride bytes (248*16 + 16; /4 = 996 ≡ 4 mod 32)
#define PLSTRIDE_DW 996

typedef __fp16 h2v __attribute__((ext_vector_type(2)));
union H2U { unsigned u; h2v h; };

// =================== shared phase bodies (device inline) ===================

__device__ __forceinline__ void phase_hist(const int* __restrict__ idx_k,
                                           int* __restrict__ hist, int nnz,
                                           int b, int tid, int* h /*LDS 256*/) {
    h[tid] = 0;
    __syncthreads();
    const int chunk = (nnz + CB - 1) / CB;
    const int lo = b * chunk, hi = min(nnz, lo + chunk);
    for (int t = lo + tid; t < hi; t += 256)
        atomicAdd(&h[idx_k[t]], 1);
    __syncthreads();
    hist[b * 256 + tid] = h[tid];
}

__device__ __forceinline__ void phase_sort(const int* __restrict__ hist,
                                           int* __restrict__ meta, int* __restrict__ perm,
                                           int* __restrict__ ssz, int* __restrict__ coff,
                                           int* __restrict__ glim, uint2* __restrict__ packedP,
                                           int tid, int* sz /*LDS 768*/) {
    int* ssl = sz + 256;
    int* red = ssl + 256;
    int tot = 0;
    for (int b = 0; b < CB; ++b) tot += hist[b * 256 + tid];
    sz[tid] = (tid < ALG_DIM) ? tot : 0;
    __syncthreads();
    red[tid] = sz[tid];
    __syncthreads();
    for (int off = 128; off > 0; off >>= 1) {
        if (tid < off) red[tid] = max(red[tid], red[tid + off]);
        __syncthreads();
    }
    int P = (red[0] + 7) & ~7;
    P = max(P, 8);
    P = min(P, PMAX);
    if (tid == 0) meta[0] = P;
    const int stride = P + 8;

    int rank = 0, mysz = 0;
    if (tid < ALG_DIM) {
        mysz = sz[tid];
        for (int k = 0; k < ALG_DIM; ++k) {
            int s2 = sz[k];
            rank += (s2 > mysz) || (s2 == mysz && k < tid);
        }
        perm[rank] = tid;
        ssz[rank]  = mysz;
        ssl[rank]  = mysz;
        const int base = rank * stride;
        glim[tid] = base + P;
        int run = base;
        for (int b = 0; b < CB; ++b) {
            coff[b * 256 + tid] = run;
            run += hist[b * 256 + tid];
        }
    }
    __syncthreads();
    if (tid < ALG_DIM) {
        const int by = rank / KPB;
        const int L  = by * KPB + (((rank - by * KPB) >> 4) << 4);
        const int trip = (ssl[L] + 7) & ~7;
        const int base = rank * stride;
        for (int e = mysz; e < trip + 8; ++e)
            packedP[base + e] = make_uint2(0u, 0u);
    }
}

__device__ __forceinline__ void phase_scatter(const int* __restrict__ idx_i,
                                              const int* __restrict__ idx_j,
                                              const int* __restrict__ idx_k,
                                              const float* __restrict__ coeff,
                                              const int* __restrict__ coff,
                                              const int* __restrict__ glim,
                                              uint2* __restrict__ packedP, int nnz,
                                              int b, int tid, int* cur /*LDS 512*/) {
    int* lim = cur + 256;
    cur[tid] = coff[b * 256 + tid];
    lim[tid] = glim[tid];
    __syncthreads();
    const int chunk = (nnz + CB - 1) / CB;
    const int lo = b * chunk, hi = min(nnz, lo + chunk);
    for (int t = lo + tid; t < hi; t += 256) {
        const int k = idx_k[t];
        const int pos = atomicAdd(&cur[k], 1);      // LDS atomic only
        if (pos < lim[k]) {
            const float c = coeff[t];
            H2U hc; hc.h = __builtin_amdgcn_cvt_pkrtz(c, c);
            uint2 p;
            p.x = ((unsigned)idx_i[t] << 4) | ((unsigned)idx_j[t] << 20);
            p.y = hc.u;
            packedP[pos] = p;
        }
    }
}

// Main gather for one (bx, by) tile. x,y as f16 in 4 LDS planes:
// (col i, rows 8s..8s+7) at byte s*3984 + i*16; lane q folds q*3984 into its
// base once; gather = ds_read_b128 at base + i*16 (bank window sweeps all 32
// banks as i varies). 12 VALU + 2 b128 per triple; f16 accumulators flushed
// to fp32 every 32 triples.
__device__ __forceinline__ void phase_main(const float* __restrict__ x,
                                           const float* __restrict__ y,
                                           const uint2* __restrict__ packedP,
                                           const int* __restrict__ meta,
                                           const int* __restrict__ perm,
                                           const int* __restrict__ ssz,
                                           float alpha, float* __restrict__ out,
                                           int bx, int by, int tid,
                                           unsigned* xs32 /*LDS planes*/) {
    unsigned* ys32 = xs32 + 4 * PLSTRIDE_DW;
    const int r0 = bx * ROWS;

    for (int u = tid; u < (ALG_DIM / 4) * (ROWS / 2); u += 256) {
        const int rp = u & 15;
        const int cq = u >> 4;
        const size_t ra = (size_t)(r0 + 2 * rp) * ALG_DIM + 4 * cq;
        const float4 xa = *reinterpret_cast<const float4*>(x + ra);
        const float4 xb = *reinterpret_cast<const float4*>(x + ra + ALG_DIM);
        const float4 ya = *reinterpret_cast<const float4*>(y + ra);
        const float4 yb = *reinterpret_cast<const float4*>(y + ra + ALG_DIM);
        const int pbase = (rp >> 2) * PLSTRIDE_DW + (rp & 3);
#define STG(d, XA, XB, YA, YB)                                                  \
        {                                                                       \
            const int dw = pbase + (4 * cq + (d)) * 4;                          \
            H2U hx; hx.h = __builtin_amdgcn_cvt_pkrtz(XA, XB);                  \
            H2U hy; hy.h = __builtin_amdgcn_cvt_pkrtz(YA, YB);                  \
            xs32[dw] = hx.u;                                                    \
            ys32[dw] = hy.u;                                                    \
        }
        STG(0, xa.x, xb.x, ya.x, yb.x)
        STG(1, xa.y, xb.y, ya.y, yb.y)
        STG(2, xa.z, xb.z, ya.z, yb.z)
        STG(3, xa.w, xb.w, ya.w, yb.w)
#undef STG
    }
    __syncthreads();

    const int P = meta[0];
    const int S = tid >> 2;              // stream 0..63 (owns one slot)
    const int q = tid & 3;               // my plane (rows 8q..8q+7)

    const char* xsb = reinterpret_cast<const char*>(xs32) + q * PLSTRIDE_B;
    const char* ysb = reinterpret_cast<const char*>(xs32 + 4 * PLSTRIDE_DW) + q * PLSTRIDE_B;

    if (S < KPB) {
        const int p = by * KPB + S;
        const int k = perm[p];

        const int pw   = by * KPB + ((tid >> 6) << 4);
        const int trip = __builtin_amdgcn_readfirstlane((ssz[pw] + 7) & ~7);
        const int nH   = trip >> 1;

        const uint4* tp = reinterpret_cast<const uint4*>(packedP)
                        + (size_t)p * ((size_t)(P + 8) >> 1);

        float a0 = 0.f, a1 = 0.f, a2 = 0.f, a3 = 0.f,
              a4 = 0.f, a5 = 0.f, a6 = 0.f, a7 = 0.f;

        uint4 cur = tp[0];

#define PROC(PW, PC)                                                            \
        {                                                                       \
            const unsigned ox = (PW) & 0xFFFFu;                                 \
            const unsigned oy = (PW) >> 16;                                     \
            const uint4 wx = *reinterpret_cast<const uint4*>(xsb + ox);         \
            const uint4 wy = *reinterpret_cast<const uint4*>(ysb + oy);         \
            H2U cc; cc.u = (PC);                                                \
            H2U ux, uy;                                                         \
            ux.u = wx.x; uy.u = wy.x; c0 = (ux.h * uy.h) * cc.h + c0;           \
            ux.u = wx.y; uy.u = wy.y; c1 = (ux.h * uy.h) * cc.h + c1;           \
            ux.u = wx.z; uy.u = wy.z; c2 = (ux.h * uy.h) * cc.h + c2;           \
            ux.u = wx.w; uy.u = wy.w; c3 = (ux.h * uy.h) * cc.h + c3;           \
        }
        for (int ch = 0; ch < nH; ch += 16) {            // 32-triple window
            h2v c0 = (h2v)0.0f, c1 = (h2v)0.0f, c2 = (h2v)0.0f, c3 = (h2v)0.0f;
            const int hend = min(ch + 16, nH);
#pragma unroll 2
            for (int h = ch; h < hend; ++h) {
                const uint4 nxt = tp[h + 1];  // prefetch (pads cover over-read)
                PROC(cur.x, cur.y)
                PROC(cur.z, cur.w)
                cur = nxt;
            }
            a0 += (float)c0.x; a1 += (float)c0.y;
            a2 += (float)c1.x; a3 += (float)c1.y;
            a4 += (float)c2.x; a5 += (float)c2.y;
            a6 += (float)c3.x; a7 += (float)c3.y;
        }
#undef PROC

        const int rbase = r0 + (q << 3);
        out[(size_t)(rbase + 0) * ALG_DIM + k] = alpha * a0;
        out[(size_t)(rbase + 1) * ALG_DIM + k] = alpha * a1;
        out[(size_t)(rbase + 2) * ALG_DIM + k] = alpha * a2;
        out[(size_t)(rbase + 3) * ALG_DIM + k] = alpha * a3;
        out[(size_t)(rbase + 4) * ALG_DIM + k] = alpha * a4;
        out[(size_t)(rbase + 5) * ALG_DIM + k] = alpha * a5;
        out[(size_t)(rbase + 6) * ALG_DIM + k] = alpha * a6;
        out[(size_t)(rbase + 7) * ALG_DIM + k] = alpha * a7;
    }
}

// =================== cooperative all-in-one kernel ===================
// Grid-stride phase D: works for ANY co-resident grid size (no exact-fit
// requirement — round 11's silent-failure mode). Phases A-C reuse phase D's
// 31.9 KB LDS block.

__global__ __launch_bounds__(256, 4) void k_all(
    const float* __restrict__ x, const float* __restrict__ y,
    const int* __restrict__ idx_i, const int* __restrict__ idx_j,
    const int* __restrict__ idx_k, const float* __restrict__ coeff,
    const float* __restrict__ alpha_p, float* __restrict__ out,
    int* __restrict__ hist, int* __restrict__ meta, int* __restrict__ perm,
    int* __restrict__ ssz, int* __restrict__ coff, int* __restrict__ glim,
    uint2* __restrict__ packedP, int nnz, int batch)
{
    __shared__ __align__(16) char SMEM[8 * PLSTRIDE_DW * 4];   // 31872 B
    cg::grid_group gg = cg::this_grid();
    const int tid = threadIdx.x;
    const int gid = blockIdx.x;

    if (gid < CB)
        phase_hist(idx_k, hist, nnz, gid, tid, (int*)SMEM);
    gg.sync();

    if (gid == 0)
        phase_sort(hist, meta, perm, ssz, coff, glim, packedP, tid, (int*)SMEM);
    gg.sync();

    if (gid < CB)
        phase_scatter(idx_i, idx_j, idx_k, coeff, coff, glim, packedP, nnz,
                      gid, tid, (int*)SMEM);
    gg.sync();

    const float alpha = alpha_p[0];
    const int nxb = batch / ROWS;
    const int ntiles = nxb * KSPLIT;
    for (int tile = gid; tile < ntiles; tile += gridDim.x) {
        __syncthreads();                 // protect LDS from previous tile's readers
        phase_main(x, y, packedP, meta, perm, ssz, alpha, out,
                   tile % nxb, tile / nxb, tid, (unsigned*)SMEM);
    }
}

// =================== fallback kernels (round-10 proven path) ===================

__global__ void k_hist_f(const int* __restrict__ idx_k, int* __restrict__ hist, int nnz) {
    __shared__ int h[256];
    phase_hist(idx_k, hist, nnz, blockIdx.x, threadIdx.x, h);
}

__global__ void k_sort_f(const int* __restrict__ hist, int* __restrict__ meta,
                         int* __restrict__ perm, int* __restrict__ ssz,
                         int* __restrict__ coff, int* __restrict__ glim,
                         uint2* __restrict__ packedP) {
    __shared__ int sz[768];
    phase_sort(hist, meta, perm, ssz, coff, glim, packedP, threadIdx.x, sz);
}

__global__ void k_scatter_f(const int* __restrict__ idx_i, const int* __restrict__ idx_j,
                            const int* __restrict__ idx_k, const float* __restrict__ coeff,
                            const int* __restrict__ coff, const int* __restrict__ glim,
                            uint2* __restrict__ packedP, int nnz) {
    __shared__ int cur[512];
    phase_scatter(idx_i, idx_j, idx_k, coeff, coff, glim, packedP, nnz,
                  blockIdx.x, threadIdx.x, cur);
}

__global__ __launch_bounds__(256, 4) void k_main_f(
    const float* __restrict__ x, const float* __restrict__ y,
    const uint2* __restrict__ packedP,
    const int* __restrict__ meta, const int* __restrict__ perm,
    const int* __restrict__ ssz,
    const float* __restrict__ alpha_p, float* __restrict__ out)
{
    __shared__ __align__(16) unsigned SM[8 * PLSTRIDE_DW];
    phase_main(x, y, packedP, meta, perm, ssz, alpha_p[0], out,
               blockIdx.x, blockIdx.y, threadIdx.x, SM);
}

// =================== launch ===================

extern "C" void kernel_launch(void* const* d_in, const int* in_sizes, int n_in,
                              void* d_out, int out_size, void* d_ws, size_t ws_size,
                              hipStream_t stream) {
    const float* x      = (const float*)d_in[0];
    const float* y      = (const float*)d_in[1];
    const int*   idx_i  = (const int*)d_in[2];
    const int*   idx_j  = (const int*)d_in[3];
    const int*   idx_k  = (const int*)d_in[4];
    const float* coeff  = (const float*)d_in[5];
    const float* alpha  = (const float*)d_in[6];
    float*       out    = (float*)d_out;

    int nnz   = in_sizes[2];
    int batch = in_sizes[0] / ALG_DIM;

    // ws: [meta @0][perm @1K][ssz @2K][glim @3K][hist @4K, 32K][coff @36864, 32K][packedP @69632]
    char*  ws      = (char*)d_ws;
    int*   meta    = (int*)ws;
    int*   perm    = (int*)(ws + 1024);
    int*   ssz     = (int*)(ws + 2048);
    int*   glim    = (int*)(ws + 3072);
    int*   hist    = (int*)(ws + 4096);
    int*   coff    = (int*)(ws + 4096 + CB * 256 * 4);
    uint2* packedP = (uint2*)(ws + 4096 + 2 * CB * 256 * 4 + 1024);

    const int ntiles = (batch / ROWS) * KSPLIT;    // 1024

    // Capacity-aware cooperative launch (host-only queries: capture-safe,
    // deterministic -> same path every call).
    int dev = 0;
    (void)hipGetDevice(&dev);
    int numCU = 0, maxb = 0;
    (void)hipDeviceGetAttribute(&numCU, hipDeviceAttributeMultiprocessorCount, dev);
    (void)hipOccupancyMaxActiveBlocksPerMultiprocessor(&maxb, (const void*)k_all, 256, 0);

    hipError_t err = hipErrorUnknown;
    if (numCU > 0 && maxb > 0) {
        int grid = maxb * numCU;
        if (grid > ntiles) grid = ntiles;
        void* args[] = { &x, &y, &idx_i, &idx_j, &idx_k, &coeff, &alpha, &out,
                         &hist, &meta, &perm, &ssz, &coff, &glim, &packedP,
                         &nnz, &batch };
        err = hipLaunchCooperativeKernel((const void*)k_all, dim3(grid), dim3(256),
                                         args, 0, stream);
    }

    if (err != hipSuccess) {
        // proven 4-dispatch path (round 10): bitwise-identical output
        k_hist_f   <<<CB, 256, 0, stream>>>(idx_k, hist, nnz);
        k_sort_f   <<<1, 256, 0, stream>>>(hist, meta, perm, ssz, coff, glim, packedP);
        k_scatter_f<<<CB, 256, 0, stream>>>(idx_i, idx_j, idx_k, coeff, coff, glim,
                                            packedP, nnz);
        dim3 grid(batch / ROWS, KSPLIT);
        k_main_f<<<grid, 256, 0, stream>>>(x, y, packedP, meta, perm, ssz, alpha, out);
    }
}

// Round 14
// 130.074 us; speedup vs baseline: 2.7992x; 2.7992x over previous
//
#include <hip/hip_runtime.h>

#define ALG_DIM 248
#define ROWS 32                    // rows per main-kernel block
#define KSPLIT 4
#define KPB 62                     // k-slots per block (248/4)
#define PMAX 1024                  // safety clamp for padded bucket length
#define CB 16                      // prep chunks (= waves in k_prep, blocks in k_scatter)
#define PLSTRIDE_B 3984            // plane stride bytes (248*16 + 16; /4 = 996 ≡ 4 mod 32)
#define PLSTRIDE_DW 996

typedef __fp16 h2v __attribute__((ext_vector_type(2)));
union H2U { unsigned u; h2v h; };

// ---------- prep 1/2: ONE block fuses histogram + sort + cursors + pads ----------
// 1024 threads = 16 waves. Wave w builds a private LDS histogram of chunk w
// (no cross-wave contention); then the block rank-sorts buckets descending,
// emits perm/ssz, per-(chunk,k) scatter cursors coff, overflow limits glim,
// and writes each slot's zero-pad tail [size, trip+8). The histogram never
// touches global memory. Round-13 lesson: grid.sync() costs ~100 us on this
// runtime — kernel boundaries (~3-5 us) are the cheap sync primitive here.

__global__ __launch_bounds__(1024) void k_prep(
    const int* __restrict__ idx_k, int* __restrict__ meta,
    int* __restrict__ perm, int* __restrict__ ssz,
    int* __restrict__ coff, int* __restrict__ glim,
    uint2* __restrict__ packedP, int nnz)
{
    __shared__ int h[CB * 256];        // per-wave histograms (16 KB)
    __shared__ int sz[256];            // bucket size by original k
    __shared__ int ssl[256];           // bucket size by slot (sorted)
    __shared__ int red[256];
    const int tid = threadIdx.x;

    for (int u = tid; u < CB * 256; u += 1024) h[u] = 0;
    __syncthreads();

    const int w = tid >> 6, lane = tid & 63;
    const int chunk = (nnz + CB - 1) / CB;
    const int lo = w * chunk, hi = min(nnz, lo + chunk);
    for (int t = lo + lane; t < hi; t += 64)
        atomicAdd(&h[(w << 8) + idx_k[t]], 1);
    __syncthreads();

    if (tid < 256) {
        int tot = 0;
        for (int b = 0; b < CB; ++b) tot += h[b * 256 + tid];
        sz[tid] = (tid < ALG_DIM) ? tot : 0;
        red[tid] = sz[tid];
    }
    __syncthreads();
    for (int off = 128; off > 0; off >>= 1) {
        if (tid < off) red[tid] = max(red[tid], red[tid + off]);
        __syncthreads();
    }
    int P = (red[0] + 7) & ~7;
    P = max(P, 8);
    P = min(P, PMAX);
    if (tid == 0) meta[0] = P;
    const int stride = P + 8;          // per-slot element stride

    int rank = 0, mysz = 0;
    if (tid < ALG_DIM) {
        mysz = sz[tid];
        for (int k = 0; k < ALG_DIM; ++k) {
            int s2 = sz[k];
            rank += (s2 > mysz) || (s2 == mysz && k < tid);   // unique ranks
        }
        perm[rank] = tid;
        ssz[rank]  = mysz;
        ssl[rank]  = mysz;
        const int base = rank * stride;
        glim[tid] = base + P;          // overflow limit (only if P clamped)
        int run = base;
        for (int b = 0; b < CB; ++b) {
            coff[b * 256 + tid] = run;
            run += h[b * 256 + tid];
        }
    }
    __syncthreads();
    if (tid < ALG_DIM) {
        // pad my slot: trip = round8(size of my 16-group's leader slot)
        const int by = rank / KPB;
        const int L  = by * KPB + (((rank - by * KPB) >> 4) << 4);
        const int trip = (ssl[L] + 7) & ~7;
        const int base = rank * stride;
        for (int e = mysz; e < trip + 8; ++e)
            packedP[base + e] = make_uint2(0u, 0u);
    }
}

// ---------- prep 2/2: scatter via LDS cursors (deterministic, no global atomics) ----------
// packed.x: lo16 = i*16, hi16 = j*16 (within-plane byte offsets);
// packed.y: coeff duplicated as f16x2.

__global__ void k_scatter(const int* __restrict__ idx_i, const int* __restrict__ idx_j,
                          const int* __restrict__ idx_k, const float* __restrict__ coeff,
                          const int* __restrict__ coff, const int* __restrict__ glim,
                          uint2* __restrict__ packedP, int nnz) {
    __shared__ int cur[256];
    __shared__ int lim[256];
    const int b = blockIdx.x, tid = threadIdx.x;
    cur[tid] = coff[b * 256 + tid];
    lim[tid] = glim[tid];              // rows >= 248 never referenced
    __syncthreads();
    const int chunk = (nnz + CB - 1) / CB;
    const int lo = b * chunk, hi = min(nnz, lo + chunk);
    for (int t = lo + tid; t < hi; t += 256) {
        const int k = idx_k[t];
        const int pos = atomicAdd(&cur[k], 1);      // LDS atomic only
        if (pos < lim[k]) {
            const float c = coeff[t];
            H2U hc; hc.h = __builtin_amdgcn_cvt_pkrtz(c, c);
            uint2 p;
            p.x = ((unsigned)idx_i[t] << 4) | ((unsigned)idx_j[t] << 20);
            p.y = hc.u;
            packedP[pos] = p;
        }
    }
}

// ---------- main: plane-layout f16 gather (unchanged from round 10) ----------
// 256 threads = 64 streams x 4 lanes over 32 rows x 62 slots. x,y as f16 in
// 4 LDS planes: (col i, rows 8s..8s+7) at byte s*3984 + i*16. Lane q folds
// q*3984 into its base once; gather = ds_read_b128 at base + i*16, bank
// window (i*4 + 4q) mod 32 sweeps all 32 banks as i varies. 12 VALU + 2 b128
// per triple; f16 accumulators flushed to fp32 every 32 triples.

__global__ __launch_bounds__(256, 4) void k_main(
    const float* __restrict__ x, const float* __restrict__ y,
    const uint4* __restrict__ packed4,
    const int* __restrict__ meta, const int* __restrict__ perm,
    const int* __restrict__ ssz,
    const float* __restrict__ alpha_p, float* __restrict__ out)
{
    __shared__ __align__(16) unsigned xs32[4 * PLSTRIDE_DW];
    __shared__ __align__(16) unsigned ys32[4 * PLSTRIDE_DW];

    const int tid = threadIdx.x;
    const int r0  = blockIdx.x * ROWS;

    for (int u = tid; u < (ALG_DIM / 4) * (ROWS / 2); u += 256) {
        const int rp = u & 15;
        const int cq = u >> 4;
        const size_t ra = (size_t)(r0 + 2 * rp) * ALG_DIM + 4 * cq;
        const float4 xa = *reinterpret_cast<const float4*>(x + ra);
        const float4 xb = *reinterpret_cast<const float4*>(x + ra + ALG_DIM);
        const float4 ya = *reinterpret_cast<const float4*>(y + ra);
        const float4 yb = *reinterpret_cast<const float4*>(y + ra + ALG_DIM);
        const int pbase = (rp >> 2) * PLSTRIDE_DW + (rp & 3);
#define STG(d, XA, XB, YA, YB)                                                  \
        {                                                                       \
            const int dw = pbase + (4 * cq + (d)) * 4;                          \
            H2U hx; hx.h = __builtin_amdgcn_cvt_pkrtz(XA, XB);                  \
            H2U hy; hy.h = __builtin_amdgcn_cvt_pkrtz(YA, YB);                  \
            xs32[dw] = hx.u;                                                    \
            ys32[dw] = hy.u;                                                    \
        }
        STG(0, xa.x, xb.x, ya.x, yb.x)
        STG(1, xa.y, xb.y, ya.y, yb.y)
        STG(2, xa.z, xb.z, ya.z, yb.z)
        STG(3, xa.w, xb.w, ya.w, yb.w)
#undef STG
    }
    __syncthreads();

    const int   P     = meta[0];
    const float alpha = alpha_p[0];
    const int   S     = tid >> 2;            // stream 0..63 (owns one slot)
    const int   q     = tid & 3;             // my plane (rows 8q..8q+7)

    const char* xsb = reinterpret_cast<const char*>(xs32) + q * PLSTRIDE_B;
    const char* ysb = reinterpret_cast<const char*>(ys32) + q * PLSTRIDE_B;

    if (S < KPB) {
        const int p = blockIdx.y * KPB + S;
        const int k = perm[p];

        const int pw   = blockIdx.y * KPB + ((tid >> 6) << 4);
        const int trip = __builtin_amdgcn_readfirstlane((ssz[pw] + 7) & ~7);
        const int nH   = trip >> 1;          // uint4s (2 triples each)

        const uint4* tp = packed4 + (size_t)p * ((size_t)(P + 8) >> 1);

        float a0 = 0.f, a1 = 0.f, a2 = 0.f, a3 = 0.f,
              a4 = 0.f, a5 = 0.f, a6 = 0.f, a7 = 0.f;

        uint4 cur = tp[0];

#define PROC(PW, PC)                                                            \
        {                                                                       \
            const unsigned ox = (PW) & 0xFFFFu;                                 \
            const unsigned oy = (PW) >> 16;                                     \
            const uint4 wx = *reinterpret_cast<const uint4*>(xsb + ox);         \
            const uint4 wy = *reinterpret_cast<const uint4*>(ysb + oy);         \
            H2U cc; cc.u = (PC);                                                \
            H2U ux, uy;                                                         \
            ux.u = wx.x; uy.u = wy.x; c0 = (ux.h * uy.h) * cc.h + c0;           \
            ux.u = wx.y; uy.u = wy.y; c1 = (ux.h * uy.h) * cc.h + c1;           \
            ux.u = wx.z; uy.u = wy.z; c2 = (ux.h * uy.h) * cc.h + c2;           \
            ux.u = wx.w; uy.u = wy.w; c3 = (ux.h * uy.h) * cc.h + c3;           \
        }

        for (int ch = 0; ch < nH; ch += 16) {            // 32-triple window
            h2v c0 = (h2v)0.0f, c1 = (h2v)0.0f, c2 = (h2v)0.0f, c3 = (h2v)0.0f;
            const int hend = min(ch + 16, nH);
#pragma unroll 2
            for (int hh = ch; hh < hend; ++hh) {
                const uint4 nxt = tp[hh + 1];  // prefetch (pads cover over-read)
                PROC(cur.x, cur.y)
                PROC(cur.z, cur.w)
                cur = nxt;
            }
            a0 += (float)c0.x; a1 += (float)c0.y;
            a2 += (float)c1.x; a3 += (float)c1.y;
            a4 += (float)c2.x; a5 += (float)c2.y;
            a6 += (float)c3.x; a7 += (float)c3.y;
        }
#undef PROC

        const int rbase = r0 + (q << 3);
        out[(size_t)(rbase + 0) * ALG_DIM + k] = alpha * a0;
        out[(size_t)(rbase + 1) * ALG_DIM + k] = alpha * a1;
        out[(size_t)(rbase + 2) * ALG_DIM + k] = alpha * a2;
        out[(size_t)(rbase + 3) * ALG_DIM + k] = alpha * a3;
        out[(size_t)(rbase + 4) * ALG_DIM + k] = alpha * a4;
        out[(size_t)(rbase + 5) * ALG_DIM + k] = alpha * a5;
        out[(size_t)(rbase + 6) * ALG_DIM + k] = alpha * a6;
        out[(size_t)(rbase + 7) * ALG_DIM + k] = alpha * a7;
    }
}

// ---------- launch ----------

extern "C" void kernel_launch(void* const* d_in, const int* in_sizes, int n_in,
                              void* d_out, int out_size, void* d_ws, size_t ws_size,
                              hipStream_t stream) {
    const float* x      = (const float*)d_in[0];
    const float* y      = (const float*)d_in[1];
    const int*   idx_i  = (const int*)d_in[2];
    const int*   idx_j  = (const int*)d_in[3];
    const int*   idx_k  = (const int*)d_in[4];
    const float* coeff  = (const float*)d_in[5];
    const float* alpha  = (const float*)d_in[6];
    float*       out    = (float*)d_out;

    const int nnz   = in_sizes[2];
    const int batch = in_sizes[0] / ALG_DIM;

    // ws: [meta @0][perm @1K][ssz @2K][glim @3K][coff @4K, 16K][packedP @24576]
    char*  ws      = (char*)d_ws;
    int*   meta    = (int*)ws;
    int*   perm    = (int*)(ws + 1024);
    int*   ssz     = (int*)(ws + 2048);
    int*   glim    = (int*)(ws + 3072);
    int*   coff    = (int*)(ws + 4096);
    uint2* packedP = (uint2*)(ws + 4096 + CB * 256 * 4 + 4096);

    k_prep   <<<1, 1024, 0, stream>>>(idx_k, meta, perm, ssz, coff, glim,
                                      packedP, nnz);
    k_scatter<<<CB, 256, 0, stream>>>(idx_i, idx_j, idx_k, coeff, coff, glim,
                                      packedP, nnz);

    dim3 grid(batch / ROWS, KSPLIT);
    k_main<<<grid, 256, 0, stream>>>(x, y, (const uint4*)packedP, meta, perm, ssz,
                                     alpha, out);
}